// Round 1
// baseline (2282.436 us; speedup 1.0000x reference)
//
#include <hip/hip_runtime.h>

#define B_   256
#define HID  512
#define T_   32
#define L_   256
#define NC   97
#define G4   2048

// d_out layout (f32): g [256,32,97] | output_hiddens [256,32,512] | masks [256,32,8,32]
#define OH_OFF   794624
#define MASK_OFF 4988928

typedef __bf16 v8bf __attribute__((ext_vector_type(8)));
typedef float  v4f  __attribute__((ext_vector_type(4)));

__device__ __forceinline__ unsigned short f2bf(float x){
  unsigned u = __float_as_uint(x);
  u += 0x7FFFu + ((u >> 16) & 1u);          // round-to-nearest-even
  return (unsigned short)(u >> 16);
}
__device__ __forceinline__ float bf2f(unsigned short h){
  return __uint_as_float(((unsigned)h) << 16);
}
__device__ __forceinline__ float sigm(float x){ return 1.f / (1.f + __expf(-x)); }
__device__ __forceinline__ float tanh_f(float x){
  float e = __expf(2.f * x);
  return 1.f - 2.f / (e + 1.f);             // safe at +/-inf
}

// ---------------------------------------------------------------- one-time --
// weights -> bf16; Wcat1[n][0:512]=W_ih1[n][:], Wcat1[n][512:1024]=W_hh1[n][:]
__global__ void k_wconv(const float* __restrict__ Whh0, const float* __restrict__ Wih1,
                        const float* __restrict__ Whh1,
                        unsigned short* __restrict__ Whh0bf, unsigned short* __restrict__ Wcat1bf){
  int i = blockIdx.x * 256 + threadIdx.x;
  if (i >= G4 * HID) return;
  Whh0bf[i] = f2bf(Whh0[i]);
  int n = i >> 9, k = i & 511;
  Wcat1bf[(size_t)n * 1024 + k]       = f2bf(Wih1[i]);
  Wcat1bf[(size_t)n * 1024 + 512 + k] = f2bf(Whh1[i]);
}

// emb_gates[c][n] = sum_h (emb_W[h][c]+emb_b[h]) * W_ih0[n][h] + b_ih0[n] + b_hh0[n]
__global__ void k_embg(const float* __restrict__ embW, const float* __restrict__ embb,
                       const float* __restrict__ Wih0, const float* __restrict__ bih0,
                       const float* __restrict__ bhh0, float* __restrict__ embg){
  int o = blockIdx.x * 256 + threadIdx.x;
  if (o >= NC * G4) return;
  int c = o / G4, n = o - c * G4;
  float s = bih0[n] + bhh0[n];
  const float4* w4 = (const float4*)(Wih0 + (size_t)n * HID);
  for (int h = 0; h < HID; h += 4){
    float4 w = w4[h >> 2];
    s += (embW[(h+0)*NC + c] + embb[h+0]) * w.x
       + (embW[(h+1)*NC + c] + embb[h+1]) * w.y
       + (embW[(h+2)*NC + c] + embb[h+2]) * w.z
       + (embW[(h+3)*NC + c] + embb[h+3]) * w.w;
  }
  embg[o] = s;
}

// origin[b][c][l] f32  ->  fmapT[b][l][c] bf16   (32x32 LDS tile transpose)
__global__ void k_fmapT(const float* __restrict__ orig, unsigned short* __restrict__ fT){
  __shared__ float tile[32][33];
  int b = blockIdx.z, c0 = blockIdx.y * 32, l0 = blockIdx.x * 32;
  const float* src = orig + ((size_t)b * HID + c0) * L_ + l0;
  for (int i = 0; i < 32; i += 8)
    tile[threadIdx.y + i][threadIdx.x] = src[(threadIdx.y + i) * L_ + threadIdx.x];
  __syncthreads();
  unsigned short* dst = fT + ((size_t)b * L_ + l0) * HID + c0;
  for (int i = 0; i < 32; i += 8)
    dst[(threadIdx.y + i) * HID + threadIdx.x] = f2bf(tile[threadIdx.x][threadIdx.y + i]);
}

// ---------------------------------------------------------- per-step LSTM ---
// MODE 0: gates = emb_gates[text[b,t]] + h0_old @ Whh0^T            (K=512)
// MODE 1: gates = (b_ih1+b_hh1) + [h0_new,h1_old] @ [Wih1|Whh1]^T   (K=1024)
// Block: 256 thr = 4 waves; wave w computes gate chunk w, tile 64 rows x 16 j.
// Fused LSTM cell epilogue via LDS. grid (4, 32).
template<int MODE>
__global__ void __launch_bounds__(256)
k_lstm(const unsigned short* __restrict__ hA1, const unsigned short* __restrict__ hA2,
       const unsigned short* __restrict__ Wbf,
       const float* __restrict__ embg, const int* __restrict__ text,
       const float* __restrict__ bia, const float* __restrict__ bib,
       float* __restrict__ cstate, unsigned short* __restrict__ hbf_out,
       float* __restrict__ h1f, int t){
  const int KS = MODE ? 32 : 16;
  const int wstride = MODE ? 1024 : 512;
  int m0 = blockIdx.x * 64, j0 = blockIdx.y * 16;
  int tid = threadIdx.x, w = tid >> 6, l = tid & 63;
  int lr = l & 15, lk = l >> 4;
  int n = w * HID + j0 + lr;                 // output gate column (0..2047)

  v4f acc[4] = {{0,0,0,0},{0,0,0,0},{0,0,0,0},{0,0,0,0}};
  for (int ks = 0; ks < KS; ++ks){
    int kb = ks * 32 + lk * 8;
    v8bf bfrag = *reinterpret_cast<const v8bf*>(Wbf + (size_t)n * wstride + kb);
    const unsigned short* Ap = (MODE == 1 && ks >= 16) ? hA2 : hA1;
    int ka = (MODE == 1 && ks >= 16) ? (kb - 512) : kb;
#pragma unroll
    for (int fm = 0; fm < 4; ++fm){
      v8bf afrag = *reinterpret_cast<const v8bf*>(Ap + (size_t)(m0 + fm*16 + lr) * HID + ka);
      acc[fm] = __builtin_amdgcn_mfma_f32_16x16x32_bf16(afrag, bfrag, acc[fm], 0, 0, 0);
    }
  }

  __shared__ float gbuf[4][64][16];
#pragma unroll
  for (int fm = 0; fm < 4; ++fm)
#pragma unroll
    for (int r = 0; r < 4; ++r)
      gbuf[w][fm*16 + lk*4 + r][lr] = acc[fm][r];   // D: row=(l>>4)*4+r, col=l&15
  __syncthreads();

  for (int e = tid; e < 1024; e += 256){
    int ml = e >> 4, jl = e & 15;
    int b = m0 + ml, j = j0 + jl;
    float xi, xf, xg, xo;
    if (MODE == 0){
      int idx = text[b * T_ + t];
      const float* eg = embg + (size_t)idx * G4 + j;
      xi = eg[0]; xf = eg[512]; xg = eg[1024]; xo = eg[1536];
    } else {
      xi = bia[j]        + bib[j];
      xf = bia[512 + j]  + bib[512 + j];
      xg = bia[1024 + j] + bib[1024 + j];
      xo = bia[1536 + j] + bib[1536 + j];
    }
    float ig = gbuf[0][ml][jl] + xi, fg = gbuf[1][ml][jl] + xf;
    float gg = gbuf[2][ml][jl] + xg, og = gbuf[3][ml][jl] + xo;
    size_t sidx = (size_t)b * HID + j;
    float cn = sigm(fg) * cstate[sidx] + sigm(ig) * tanh_f(gg);
    cstate[sidx] = cn;
    float hn = sigm(og) * tanh_f(cn);
    hbf_out[sidx] = f2bf(hn);
    if (MODE == 1) h1f[sidx] = hn;
  }
}

// ------------------------------------------------------- per-step attention -
// One block per batch, 8 waves. Single pass over fmapT rows: dot -> sigmoid ->
// accumulate context. Writes masks and output_hiddens directly.
__global__ void __launch_bounds__(512)
k_attn(const unsigned short* __restrict__ fT, const float* __restrict__ h1f,
       float* __restrict__ d_out, int t){
  int b = blockIdx.x, tid = threadIdx.x, w = tid >> 6, l = tid & 63;
  __shared__ float cbuf[8][HID];
  float hreg[8];
  const float* hp = h1f + (size_t)b * HID + l * 8;
#pragma unroll
  for (int i = 0; i < 8; ++i) hreg[i] = hp[i];
  float acc[8] = {0,0,0,0,0,0,0,0};
  const unsigned short* fb = fT + (size_t)b * L_ * HID;
  float* mout = d_out + MASK_OFF + ((size_t)b * T_ + t) * L_;

  for (int it = 0; it < L_ / 8; ++it){
    int ll = it * 8 + w;
    const unsigned short* row = fb + (size_t)ll * HID + l * 8;
    ushort4 u0 = *(const ushort4*)row;
    ushort4 u1 = *(const ushort4*)(row + 4);
    float f[8] = {bf2f(u0.x), bf2f(u0.y), bf2f(u0.z), bf2f(u0.w),
                  bf2f(u1.x), bf2f(u1.y), bf2f(u1.z), bf2f(u1.w)};
    float d = 0.f;
#pragma unroll
    for (int i = 0; i < 8; ++i) d += f[i] * hreg[i];
#pragma unroll
    for (int s = 1; s < 64; s <<= 1) d += __shfl_xor(d, s);
    float a = sigm(d);
    if (l == 0) mout[ll] = a;
#pragma unroll
    for (int i = 0; i < 8; ++i) acc[i] += a * f[i];
  }
#pragma unroll
  for (int i = 0; i < 8; ++i) cbuf[w][l * 8 + i] = acc[i];
  __syncthreads();
  float s = 0.f;
#pragma unroll
  for (int ww = 0; ww < 8; ++ww) s += cbuf[ww][tid];
  d_out[OH_OFF + ((size_t)b * T_ + t) * HID + tid] = s;
}

// fallback (only if ws too small for fmapT): two-pass f32 straight from origin
__global__ void __launch_bounds__(256)
k_attn_direct(const float* __restrict__ orig, const float* __restrict__ h1f,
              float* __restrict__ d_out, int t){
  int b = blockIdx.x, tid = threadIdx.x;
  __shared__ float h1s[HID];
  __shared__ float as[L_];
  h1s[tid] = h1f[(size_t)b * HID + tid];
  h1s[256 + tid] = h1f[(size_t)b * HID + 256 + tid];
  __syncthreads();
  const float* fb = orig + (size_t)b * HID * L_;
  float dot = 0.f;
  for (int ch = 0; ch < HID; ++ch) dot += h1s[ch] * fb[(size_t)ch * L_ + tid];
  float a = sigm(dot);
  as[tid] = a;
  d_out[MASK_OFF + ((size_t)b * T_ + t) * L_ + tid] = a;
  __syncthreads();
  for (int cc = 0; cc < 2; ++cc){
    int ch = tid + cc * 256;
    float s = 0.f;
    for (int ll = 0; ll < L_; ++ll) s += as[ll] * fb[(size_t)ch * L_ + ll];
    d_out[OH_OFF + ((size_t)b * T_ + t) * HID + ch] = s;
  }
}

// ------------------------------------------------------------------ final ---
__global__ void k_gen(const float* __restrict__ ctx, const float* __restrict__ genW,
                      const float* __restrict__ genb, float* __restrict__ g){
  int o = blockIdx.x * 256 + threadIdx.x;
  if (o >= B_ * T_ * NC) return;
  int m = o / NC, n = o - m * NC;
  const float4* a = (const float4*)(ctx + (size_t)m * HID);
  const float4* wv = (const float4*)(genW + (size_t)n * HID);
  float s = genb[n];
  for (int k = 0; k < HID / 4; ++k){
    float4 av = a[k], w = wv[k];
    s += av.x * w.x + av.y * w.y + av.z * w.z + av.w * w.w;
  }
  g[o] = s;
}

// -----------------------------------------------------------------------------
extern "C" void kernel_launch(void* const* d_in, const int* in_sizes, int n_in,
                              void* d_out, int out_size, void* d_ws, size_t ws_size,
                              hipStream_t stream){
  const float* orig = (const float*)d_in[0];
  const int*   text = (const int*)  d_in[1];
  const float* embW = (const float*)d_in[2];
  const float* embb = (const float*)d_in[3];
  const float* Wih0 = (const float*)d_in[4];
  const float* Whh0 = (const float*)d_in[5];
  const float* bih0 = (const float*)d_in[6];
  const float* bhh0 = (const float*)d_in[7];
  const float* Wih1 = (const float*)d_in[8];
  const float* Whh1 = (const float*)d_in[9];
  const float* bih1 = (const float*)d_in[10];
  const float* bhh1 = (const float*)d_in[11];
  const float* genW = (const float*)d_in[12];
  const float* genb = (const float*)d_in[13];
  float* out = (float*)d_out;

  char* p = (char*)d_ws;
  float* embg = (float*)p;            p += (size_t)NC * G4 * 4;
  float* c0   = (float*)p;            p += (size_t)B_ * HID * 4;
  float* c1   = (float*)p;            p += (size_t)B_ * HID * 4;
  unsigned short* h0bf[2];
  h0bf[0] = (unsigned short*)p;       p += (size_t)B_ * HID * 2;
  h0bf[1] = (unsigned short*)p;       p += (size_t)B_ * HID * 2;
  unsigned short* h1bf[2];
  h1bf[0] = (unsigned short*)p;       p += (size_t)B_ * HID * 2;
  h1bf[1] = (unsigned short*)p;       p += (size_t)B_ * HID * 2;
  float* h1f = (float*)p;             p += (size_t)B_ * HID * 4;
  unsigned short* Whh0bf  = (unsigned short*)p; p += (size_t)G4 * 512 * 2;
  unsigned short* Wcat1bf = (unsigned short*)p; p += (size_t)G4 * 1024 * 2;
  unsigned short* fmapT   = (unsigned short*)p; p += (size_t)B_ * L_ * HID * 2;
  bool big = ws_size >= (size_t)(p - (char*)d_ws);

  // zero c0,c1 and the four h ping-pong buffers (contiguous)
  hipMemsetAsync(c0, 0, (size_t)B_ * HID * 4 * 2 + (size_t)B_ * HID * 2 * 4, stream);

  k_wconv<<<(G4 * HID + 255) / 256, 256, 0, stream>>>(Whh0, Wih1, Whh1, Whh0bf, Wcat1bf);
  k_embg<<<(NC * G4 + 255) / 256, 256, 0, stream>>>(embW, embb, Wih0, bih0, bhh0, embg);
  if (big) k_fmapT<<<dim3(L_/32, HID/32, B_), dim3(32, 8), 0, stream>>>(orig, fmapT);

  for (int t = 0; t < T_; ++t){
    int ping = t & 1;
    k_lstm<0><<<dim3(4, 32), 256, 0, stream>>>(h0bf[ping], nullptr, Whh0bf,
        embg, text, nullptr, nullptr, c0, h0bf[ping ^ 1], nullptr, t);
    k_lstm<1><<<dim3(4, 32), 256, 0, stream>>>(h0bf[ping ^ 1], h1bf[ping], Wcat1bf,
        nullptr, nullptr, bih1, bhh1, c1, h1bf[ping ^ 1], h1f, t);
    if (big) k_attn<<<B_, 512, 0, stream>>>(fmapT, h1f, out, t);
    else     k_attn_direct<<<B_, 256, 0, stream>>>(orig, h1f, out, t);
  }
  k_gen<<<(B_ * T_ * NC + 255) / 256, 256, 0, stream>>>(out + OH_OFF, genW, genb, out);
}

// Round 2
// 1331.612 us; speedup vs baseline: 1.7140x; 1.7140x over previous
//
#include <hip/hip_runtime.h>

#define B_   256
#define HID  512
#define T_   32
#define L_   256
#define NC   97
#define G4   2048

// d_out layout (f32): g [256,32,97] | output_hiddens [256,32,512] | masks [256,32,8,32]
#define OH_OFF   794624
#define MASK_OFF 4988928

typedef __bf16 v8bf __attribute__((ext_vector_type(8)));
typedef float  v4f  __attribute__((ext_vector_type(4)));

__device__ __forceinline__ unsigned short f2bf(float x){
  unsigned u = __float_as_uint(x);
  u += 0x7FFFu + ((u >> 16) & 1u);          // round-to-nearest-even
  return (unsigned short)(u >> 16);
}
__device__ __forceinline__ float bf2f(unsigned short h){
  return __uint_as_float(((unsigned)h) << 16);
}
__device__ __forceinline__ float sigm(float x){ return 1.f / (1.f + __expf(-x)); }
__device__ __forceinline__ float tanh_f(float x){
  float e = __expf(2.f * x);
  return 1.f - 2.f / (e + 1.f);             // safe at +/-inf
}
__device__ __forceinline__ v8bf ld8(const unsigned short* p){
  return *reinterpret_cast<const v8bf*>(p);
}

// ---------------------------------------------------------------- one-time --
__global__ void k_wconv(const float* __restrict__ Whh0, const float* __restrict__ Wih1,
                        const float* __restrict__ Whh1, const float* __restrict__ Wih0,
                        unsigned short* __restrict__ Whh0bf, unsigned short* __restrict__ Wcat1bf,
                        unsigned short* __restrict__ Wih0bf){
  int i = blockIdx.x * 256 + threadIdx.x;
  if (i >= G4 * HID) return;
  Whh0bf[i] = f2bf(Whh0[i]);
  Wih0bf[i] = f2bf(Wih0[i]);
  int n = i >> 9, k = i & 511;
  Wcat1bf[(size_t)n * 1024 + k]       = f2bf(Wih1[i]);
  Wcat1bf[(size_t)n * 1024 + 512 + k] = f2bf(Whh1[i]);
}

// embX[c][h] = embW[h][c]+embb[h]; genW -> bf16; b1sum = b_ih1+b_hh1
__global__ void k_small(const float* __restrict__ embW, const float* __restrict__ embb,
                        const float* __restrict__ genW, const float* __restrict__ bih1,
                        const float* __restrict__ bhh1,
                        unsigned short* __restrict__ embXbf, unsigned short* __restrict__ genWbf,
                        float* __restrict__ b1sum){
  int i = blockIdx.x * 256 + threadIdx.x;
  if (i < NC * HID){
    int c = i >> 9, h = i & 511;
    embXbf[i] = f2bf(embW[h * NC + c] + embb[h]);
    genWbf[i] = f2bf(genW[i]);
  }
  if (i < G4) b1sum[i] = bih1[i] + bhh1[i];
}

// emb_gates[c][n] = embX[c] . Wih0[n] + b_ih0[n] + b_hh0[n]   (MFMA, M=97 N=2048 K=512)
__global__ void __launch_bounds__(64)
k_embg_m(const unsigned short* __restrict__ embXbf, const unsigned short* __restrict__ Wih0bf,
         const float* __restrict__ bih0, const float* __restrict__ bhh0,
         float* __restrict__ embg){
  int m0 = blockIdx.x * 16, j0 = blockIdx.y * 16;
  int l = threadIdx.x, lr = l & 15, lk = l >> 4;
  int ar = min(m0 + lr, NC - 1);
  v4f acc = {0,0,0,0};
  for (int ks = 0; ks < 16; ++ks){
    int kb = ks * 32 + lk * 8;
    v8bf a  = ld8(embXbf + (size_t)ar * HID + kb);
    v8bf bf = ld8(Wih0bf + (size_t)(j0 + lr) * HID + kb);
    acc = __builtin_amdgcn_mfma_f32_16x16x32_bf16(a, bf, acc, 0, 0, 0);
  }
  int n = j0 + lr;
  float bb = bih0[n] + bhh0[n];
#pragma unroll
  for (int r = 0; r < 4; ++r){
    int c = m0 + lk * 4 + r;
    if (c < NC) embg[(size_t)c * G4 + n] = acc[r] + bb;
  }
}

// origin[b][c][l] f32 -> fmapT[b][l][c] bf16
__global__ void k_fmapT(const float* __restrict__ orig, unsigned short* __restrict__ fT){
  __shared__ float tile[32][33];
  int b = blockIdx.z, c0 = blockIdx.y * 32, l0 = blockIdx.x * 32;
  const float* src = orig + ((size_t)b * HID + c0) * L_ + l0;
  for (int i = 0; i < 32; i += 8)
    tile[threadIdx.y + i][threadIdx.x] = src[(threadIdx.y + i) * L_ + threadIdx.x];
  __syncthreads();
  unsigned short* dst = fT + ((size_t)b * L_ + l0) * HID + c0;
  for (int i = 0; i < 32; i += 8)
    dst[(threadIdx.y + i) * HID + threadIdx.x] = f2bf(tile[threadIdx.x][threadIdx.y + i]);
}

// ---------------------------------------------------------- per-step LSTM ---
// 1 wave per block, grid (8,32). Wave owns 32 rows x 16 j for ALL 4 gates;
// cell epilogue pure-register (no LDS, no barriers).
// MODE 0: gates = emb_gates[text[b,t]] + h0_old @ Whh0^T            (K=512)
// MODE 1: gates = b1sum + [h0_new,h1_old] @ [Wih1|Whh1]^T           (K=1024)
template<int MODE>
__global__ void __launch_bounds__(64)
k_lstm2(const unsigned short* __restrict__ hA1, const unsigned short* __restrict__ hA2,
        const unsigned short* __restrict__ Wbf,
        const float* __restrict__ embg, const int* __restrict__ text,
        const float* __restrict__ b1sum,
        float* __restrict__ cstate, unsigned short* __restrict__ hout,
        unsigned short* __restrict__ h1all, int t){
  const int KS = MODE ? 32 : 16;
  const int wstr = MODE ? 1024 : 512;
  int m0 = blockIdx.x * 32, j0 = blockIdx.y * 16;
  int l = threadIdx.x, lr = l & 15, lk = l >> 4;
  v4f acc[2][4] = {};
  for (int ks = 0; ks < KS; ++ks){
    int kb = ks * 32 + lk * 8;
    const unsigned short* Ap = (MODE == 1 && ks >= 16) ? hA2 : hA1;
    int ka = (MODE == 1 && ks >= 16) ? (kb - 512) : kb;
    v8bf a0 = ld8(Ap + (size_t)(m0 + lr) * HID + ka);
    v8bf a1 = ld8(Ap + (size_t)(m0 + 16 + lr) * HID + ka);
#pragma unroll
    for (int g = 0; g < 4; ++g){
      v8bf bf = ld8(Wbf + (size_t)(g * HID + j0 + lr) * wstr + kb);
      acc[0][g] = __builtin_amdgcn_mfma_f32_16x16x32_bf16(a0, bf, acc[0][g], 0, 0, 0);
      acc[1][g] = __builtin_amdgcn_mfma_f32_16x16x32_bf16(a1, bf, acc[1][g], 0, 0, 0);
    }
  }
  int j = j0 + lr;
  float xi = 0.f, xf = 0.f, xg = 0.f, xo = 0.f;
  if (MODE == 1){
    xi = b1sum[j]; xf = b1sum[512 + j]; xg = b1sum[1024 + j]; xo = b1sum[1536 + j];
  }
#pragma unroll
  for (int fm = 0; fm < 2; ++fm){
#pragma unroll
    for (int r = 0; r < 4; ++r){
      int b = m0 + fm * 16 + lk * 4 + r;
      if (MODE == 0){
        const float* eg = embg + (size_t)text[b * T_ + t] * G4 + j;
        xi = eg[0]; xf = eg[512]; xg = eg[1024]; xo = eg[1536];
      }
      float ig = acc[fm][0][r] + xi, fg = acc[fm][1][r] + xf;
      float gg = acc[fm][2][r] + xg, og = acc[fm][3][r] + xo;
      size_t s = (size_t)b * HID + j;
      float cn = sigm(fg) * cstate[s] + sigm(ig) * tanh_f(gg);
      cstate[s] = cn;
      float hn = sigm(og) * tanh_f(cn);
      hout[s] = f2bf(hn);
      if (MODE == 1 && h1all != nullptr)
        h1all[((size_t)b * T_ + t) * HID + j] = f2bf(hn);
    }
  }
}

// ----------------------------------------------------- batched attention ----
// Pass 1: S[t][l] = h1all[b][t] . fmapT[b][l]  (MFMA, M=32 N=256 K=512)
// sigmoid -> masks (f32 out) + Abf (bf16)
__global__ void __launch_bounds__(256)
k_attn1(const unsigned short* __restrict__ fT, const unsigned short* __restrict__ h1all,
        unsigned short* __restrict__ Abf, float* __restrict__ d_out){
  int b = blockIdx.x, tid = threadIdx.x, w = tid >> 6, l = tid & 63;
  int lr = l & 15, lk = l >> 4;
  const unsigned short* hb = h1all + (size_t)b * T_ * HID;
  const unsigned short* fb = fT + (size_t)b * L_ * HID;
  v4f acc[2][4] = {};
  for (int ks = 0; ks < 16; ++ks){
    int kb = ks * 32 + lk * 8;
    v8bf a0 = ld8(hb + (size_t)lr * HID + kb);
    v8bf a1 = ld8(hb + (size_t)(16 + lr) * HID + kb);
#pragma unroll
    for (int fn = 0; fn < 4; ++fn){
      v8bf bf = ld8(fb + (size_t)(w * 64 + fn * 16 + lr) * HID + kb);
      acc[0][fn] = __builtin_amdgcn_mfma_f32_16x16x32_bf16(a0, bf, acc[0][fn], 0, 0, 0);
      acc[1][fn] = __builtin_amdgcn_mfma_f32_16x16x32_bf16(a1, bf, acc[1][fn], 0, 0, 0);
    }
  }
#pragma unroll
  for (int fm = 0; fm < 2; ++fm)
#pragma unroll
    for (int fn = 0; fn < 4; ++fn)
#pragma unroll
      for (int r = 0; r < 4; ++r){
        int tt = fm * 16 + lk * 4 + r;
        int li = w * 64 + fn * 16 + lr;
        float aa = sigm(acc[fm][fn][r]);
        d_out[MASK_OFF + ((size_t)b * T_ + tt) * L_ + li] = aa;
        Abf[((size_t)b * T_ + tt) * L_ + li] = f2bf(aa);
      }
}

// Pass 2: C[t][ch] = sum_l A[t][l] * fmapT[b][l][ch]  (vector; A staged in LDS)
// writes output_hiddens f32 and ctxbf bf16.
__global__ void __launch_bounds__(512)
k_attn2(const unsigned short* __restrict__ fT, const unsigned short* __restrict__ Abf,
        float* __restrict__ d_out, unsigned short* __restrict__ ctxbf){
  int b = blockIdx.x, tid = threadIdx.x, w = tid >> 6, l = tid & 63;
  __shared__ float aS[T_][L_];
  const unsigned short* ab = Abf + (size_t)b * T_ * L_;
  for (int i = tid * 8; i < T_ * L_; i += 512 * 8){
    ushort4 u0 = *(const ushort4*)(ab + i);
    ushort4 u1 = *(const ushort4*)(ab + i + 4);
    int tt = i >> 8, ll = i & 255;
    aS[tt][ll+0] = bf2f(u0.x); aS[tt][ll+1] = bf2f(u0.y);
    aS[tt][ll+2] = bf2f(u0.z); aS[tt][ll+3] = bf2f(u0.w);
    aS[tt][ll+4] = bf2f(u1.x); aS[tt][ll+5] = bf2f(u1.y);
    aS[tt][ll+6] = bf2f(u1.z); aS[tt][ll+7] = bf2f(u1.w);
  }
  __syncthreads();
  float acc[4][8] = {};
  const unsigned short* fb = fT + (size_t)b * L_ * HID + l * 8;
  for (int li = 0; li < L_; ++li){
    ushort4 u0 = *(const ushort4*)(fb + (size_t)li * HID);
    ushort4 u1 = *(const ushort4*)(fb + (size_t)li * HID + 4);
    float f[8] = {bf2f(u0.x), bf2f(u0.y), bf2f(u0.z), bf2f(u0.w),
                  bf2f(u1.x), bf2f(u1.y), bf2f(u1.z), bf2f(u1.w)};
#pragma unroll
    for (int tt = 0; tt < 4; ++tt){
      float a = aS[w * 4 + tt][li];
#pragma unroll
      for (int k = 0; k < 8; ++k) acc[tt][k] += a * f[k];
    }
  }
#pragma unroll
  for (int tt = 0; tt < 4; ++tt)
#pragma unroll
    for (int k = 0; k < 8; ++k){
      size_t o = ((size_t)b * T_ + w * 4 + tt) * HID + l * 8 + k;
      d_out[OH_OFF + o] = acc[tt][k];
      ctxbf[o] = f2bf(acc[tt][k]);
    }
}

// ------------------------------------------------------------------ final ---
// g = ctx @ genW^T + genb   (MFMA, M=8192 N=97 K=512)
__global__ void __launch_bounds__(256)
k_gen_m(const unsigned short* __restrict__ ctxbf, const unsigned short* __restrict__ genWbf,
        const float* __restrict__ genb, float* __restrict__ g){
  int m0 = blockIdx.x * 64 + (threadIdx.x >> 6) * 16;
  int j0 = blockIdx.y * 16;
  int l = threadIdx.x & 63, lr = l & 15, lk = l >> 4;
  int n = j0 + lr, nr = min(n, NC - 1);
  v4f acc = {0,0,0,0};
  for (int ks = 0; ks < 16; ++ks){
    int kb = ks * 32 + lk * 8;
    v8bf a  = ld8(ctxbf + (size_t)(m0 + lr) * HID + kb);
    v8bf bf = ld8(genWbf + (size_t)nr * HID + kb);
    acc = __builtin_amdgcn_mfma_f32_16x16x32_bf16(a, bf, acc, 0, 0, 0);
  }
  if (n < NC){
    float bb = genb[n];
#pragma unroll
    for (int r = 0; r < 4; ++r)
      g[(size_t)(m0 + lk * 4 + r) * NC + n] = acc[r] + bb;
  }
}

// --------------------------------------------------------------- fallbacks --
__global__ void __launch_bounds__(256)
k_attn_direct(const float* __restrict__ orig, const unsigned short* __restrict__ h1b,
              float* __restrict__ d_out, int t){
  int b = blockIdx.x, tid = threadIdx.x;
  __shared__ float h1s[HID];
  __shared__ float as[L_];
  h1s[tid]       = bf2f(h1b[(size_t)b * HID + tid]);
  h1s[256 + tid] = bf2f(h1b[(size_t)b * HID + 256 + tid]);
  __syncthreads();
  const float* fb = orig + (size_t)b * HID * L_;
  float dot = 0.f;
  for (int ch = 0; ch < HID; ++ch) dot += h1s[ch] * fb[(size_t)ch * L_ + tid];
  float a = sigm(dot);
  as[tid] = a;
  d_out[MASK_OFF + ((size_t)b * T_ + t) * L_ + tid] = a;
  __syncthreads();
  for (int cc = 0; cc < 2; ++cc){
    int ch = tid + cc * 256;
    float s = 0.f;
    for (int ll = 0; ll < L_; ++ll) s += as[ll] * fb[(size_t)ch * L_ + ll];
    d_out[OH_OFF + ((size_t)b * T_ + t) * HID + ch] = s;
  }
}

__global__ void k_gen_v(const float* __restrict__ ctx, const float* __restrict__ genW,
                        const float* __restrict__ genb, float* __restrict__ g){
  int o = blockIdx.x * 256 + threadIdx.x;
  if (o >= B_ * T_ * NC) return;
  int m = o / NC, n = o - m * NC;
  const float4* a = (const float4*)(ctx + (size_t)m * HID);
  const float4* wv = (const float4*)(genW + (size_t)n * HID);
  float s = genb[n];
  for (int k = 0; k < HID / 4; ++k){
    float4 av = a[k], w = wv[k];
    s += av.x * w.x + av.y * w.y + av.z * w.z + av.w * w.w;
  }
  g[o] = s;
}

// -----------------------------------------------------------------------------
extern "C" void kernel_launch(void* const* d_in, const int* in_sizes, int n_in,
                              void* d_out, int out_size, void* d_ws, size_t ws_size,
                              hipStream_t stream){
  const float* orig = (const float*)d_in[0];
  const int*   text = (const int*)  d_in[1];
  const float* embW = (const float*)d_in[2];
  const float* embb = (const float*)d_in[3];
  const float* Wih0 = (const float*)d_in[4];
  const float* Whh0 = (const float*)d_in[5];
  const float* bih0 = (const float*)d_in[6];
  const float* bhh0 = (const float*)d_in[7];
  const float* Wih1 = (const float*)d_in[8];
  const float* Whh1 = (const float*)d_in[9];
  const float* bih1 = (const float*)d_in[10];
  const float* bhh1 = (const float*)d_in[11];
  const float* genW = (const float*)d_in[12];
  const float* genb = (const float*)d_in[13];
  float* out = (float*)d_out;

  char* p = (char*)d_ws;
  float* embg  = (float*)p;           p += (size_t)NC * G4 * 4;        // 794624
  float* b1sum = (float*)p;           p += (size_t)G4 * 4;             // 8192
  float* c0    = (float*)p;           p += (size_t)B_ * HID * 4;       // states: contiguous, memset below
  float* c1    = (float*)p;           p += (size_t)B_ * HID * 4;
  unsigned short* h0bf[2];
  h0bf[0] = (unsigned short*)p;       p += (size_t)B_ * HID * 2;
  h0bf[1] = (unsigned short*)p;       p += (size_t)B_ * HID * 2;
  unsigned short* h1bf[2];
  h1bf[0] = (unsigned short*)p;       p += (size_t)B_ * HID * 2;
  h1bf[1] = (unsigned short*)p;       p += (size_t)B_ * HID * 2;
  unsigned short* Whh0bf  = (unsigned short*)p; p += (size_t)G4 * 512 * 2;
  unsigned short* Wcat1bf = (unsigned short*)p; p += (size_t)G4 * 1024 * 2;
  unsigned short* Wih0bf  = (unsigned short*)p; p += (size_t)G4 * 512 * 2;
  unsigned short* embXbf  = (unsigned short*)p; p += (size_t)NC * HID * 2;
  unsigned short* genWbf  = (unsigned short*)p; p += (size_t)NC * HID * 2;
  // big-path-only buffers
  unsigned short* h1all = (unsigned short*)p;  p += (size_t)B_ * T_ * HID * 2;  // 8MB
  unsigned short* Abf   = (unsigned short*)p;  p += (size_t)B_ * T_ * L_ * 2;   // 4MB
  unsigned short* ctxbf = (unsigned short*)p;  p += (size_t)B_ * T_ * HID * 2;  // 8MB
  unsigned short* fmapT = (unsigned short*)p;  p += (size_t)B_ * L_ * HID * 2;  // 64MB
  bool big = ws_size >= (size_t)(p - (char*)d_ws);

  // zero c0,c1,h0bf[0..1],h1bf[0..1] (contiguous region)
  hipMemsetAsync(c0, 0, (size_t)B_ * HID * 4 * 2 + (size_t)B_ * HID * 2 * 4, stream);

  k_wconv<<<(G4 * HID + 255) / 256, 256, 0, stream>>>(Whh0, Wih1, Whh1, Wih0,
                                                      Whh0bf, Wcat1bf, Wih0bf);
  k_small<<<(NC * HID + 255) / 256, 256, 0, stream>>>(embW, embb, genW, bih1, bhh1,
                                                      embXbf, genWbf, b1sum);
  k_embg_m<<<dim3(7, G4 / 16), 64, 0, stream>>>(embXbf, Wih0bf, bih0, bhh0, embg);
  if (big) k_fmapT<<<dim3(L_ / 32, HID / 32, B_), dim3(32, 8), 0, stream>>>(orig, fmapT);

  for (int t = 0; t < T_; ++t){
    int ping = t & 1;
    k_lstm2<0><<<dim3(8, 32), 64, 0, stream>>>(h0bf[ping], nullptr, Whh0bf,
        embg, text, nullptr, c0, h0bf[ping ^ 1], nullptr, t);
    k_lstm2<1><<<dim3(8, 32), 64, 0, stream>>>(h0bf[ping ^ 1], h1bf[ping], Wcat1bf,
        nullptr, nullptr, b1sum, c1, h1bf[ping ^ 1], big ? h1all : nullptr, t);
    if (!big) k_attn_direct<<<B_, 256, 0, stream>>>(orig, h1bf[ping ^ 1], out, t);
  }

  if (big){
    k_attn1<<<B_, 256, 0, stream>>>(fmapT, h1all, Abf, out);
    k_attn2<<<B_, 512, 0, stream>>>(fmapT, Abf, out, ctxbf);
    k_gen_m<<<dim3(B_ * T_ / 64, 7), 256, 0, stream>>>(ctxbf, genWbf, genb, out);
  } else {
    k_gen_v<<<(B_ * T_ * NC + 255) / 256, 256, 0, stream>>>(out + OH_OFF, genW, genb, out);
  }
}